// Round 1
// baseline (474.587 us; speedup 1.0000x reference)
//
#include <hip/hip_runtime.h>

#define B_    16
#define L_    2048
#define S_    1024
#define DE_   512
#define D_    256
#define NSIL_ 8
#define A_    64

#define ROWS1 8     // rows per block, kernel 1
#define ROWS2 16    // rows per block, kernel 2

// ---------------------------------------------------------------------------
// Kernel 1: handle t==0 / t==1 (and t>=3 zeros) rows directly; compact t==2
// row indices into a worklist.
// ---------------------------------------------------------------------------
__global__ __launch_bounds__(256) void srse_gather_compact(
    const float* __restrict__ op_emb,      // (VOP, D)
    const float* __restrict__ silent,      // (NSIL, D)
    const float* __restrict__ nodes,       // (NN, D)
    const int*   __restrict__ op_tokens,   // (B*L)
    const int*   __restrict__ arg_idx,     // (B*L)
    const int*   __restrict__ item_type,   // (B*L)
    const int*   __restrict__ avail_nodes, // (B*L, A)
    float*       __restrict__ out,         // (B*L, D)
    int*         __restrict__ cnt,
    int*         __restrict__ wl)
{
    const int d    = threadIdx.x;
    const int row0 = blockIdx.x * ROWS1;

    #pragma unroll
    for (int r = 0; r < ROWS1; ++r) {
        const int row = row0 + r;
        const int t   = item_type[row];        // wave-uniform -> s_load
        if (t == 2) {
            if (d == 0) {
                int p = atomicAdd(cnt, 1);
                wl[p] = row;
            }
            continue;                           // kernel 2 writes this row
        }
        float v = 0.0f;
        if (t == 0) {
            v = op_emb[op_tokens[row] * D_ + d];
        } else if (t == 1) {
            int a = arg_idx[row];
            if (a < NSIL_) {
                v = silent[a * D_ + d];
            } else {
                int np = a - NSIL_;
                if (np > A_ - 1) np = A_ - 1;
                int nid = avail_nodes[row * A_ + np];   // single int per row
                v = nodes[(size_t)nid * D_ + d];
            }
        }
        out[(size_t)row * D_ + d] = v;
    }
}

// ---------------------------------------------------------------------------
// Kernel 2: batched mat-vec for t==2 rows. 16 rows per block; w_shift column
// loads amortized 16x; sentence operands wave-uniform -> SGPR broadcasts.
// ---------------------------------------------------------------------------
__global__ __launch_bounds__(256) void srse_shift_mm(
    const float* __restrict__ sent,      // (B, S, DE)
    const float* __restrict__ w,         // (DE, D)
    const float* __restrict__ bsh,       // (D)
    const int*   __restrict__ shift_idx, // (B*L)
    const int*   __restrict__ cnt,
    const int*   __restrict__ wl,
    float*       __restrict__ out)       // (B*L, D)
{
    const int n  = *cnt;
    const int i0 = blockIdx.x * ROWS2;
    if (i0 >= n) return;

    const int d = threadIdx.x;
    const int m = min(ROWS2, n - i0);
    const float bval = bsh[d];

    int          rows[ROWS2];
    const float* base[ROWS2];
    float        acc[ROWS2];

    #pragma unroll
    for (int r = 0; r < ROWS2; ++r) {
        int idx = i0 + (r < m ? r : m - 1);          // clamp tail (dup rows)
        int row = __builtin_amdgcn_readfirstlane(wl[idx]);
        rows[r] = row;
        int b   = row >> 11;                          // row / L_
        int s   = shift_idx[row];
        int off = __builtin_amdgcn_readfirstlane(b * S_ + s);
        base[r] = sent + (size_t)off * DE_;
        acc[r]  = bval;
    }

    for (int e = 0; e < DE_; e += 8) {
        float wv[8];
        #pragma unroll
        for (int ee = 0; ee < 8; ++ee)
            wv[ee] = w[(e + ee) * D_ + d];            // coalesced, L2-hot
        #pragma unroll
        for (int r = 0; r < ROWS2; ++r) {
            #pragma unroll
            for (int ee = 0; ee < 8; ++ee)
                acc[r] += base[r][e + ee] * wv[ee];   // s_load_dwordx8 + v_fmac
        }
    }

    #pragma unroll
    for (int r = 0; r < ROWS2; ++r) {                 // static idx (rule #20)
        if (r < m)
            out[(size_t)rows[r] * D_ + d] = acc[r];
    }
}

// ---------------------------------------------------------------------------
extern "C" void kernel_launch(void* const* d_in, const int* in_sizes, int n_in,
                              void* d_out, int out_size, void* d_ws, size_t ws_size,
                              hipStream_t stream) {
    const float* sent      = (const float*)d_in[0];
    const float* nodes     = (const float*)d_in[1];
    const float* silent    = (const float*)d_in[2];
    const float* op_emb    = (const float*)d_in[3];
    const float* w         = (const float*)d_in[4];
    const float* bsh       = (const float*)d_in[5];
    const int*   op_tokens = (const int*)d_in[6];
    const int*   arg_idx   = (const int*)d_in[7];
    const int*   shift_idx = (const int*)d_in[8];
    const int*   item_type = (const int*)d_in[9];
    const int*   avail     = (const int*)d_in[10];
    float*       out       = (float*)d_out;

    int* cnt = (int*)d_ws;           // 1 int counter
    int* wl  = (int*)d_ws + 16;      // worklist (<= 32768 ints)

    hipMemsetAsync(cnt, 0, sizeof(int), stream);

    const int nrows = B_ * L_;
    srse_gather_compact<<<nrows / ROWS1, 256, 0, stream>>>(
        op_emb, silent, nodes, op_tokens, arg_idx, item_type, avail,
        out, cnt, wl);

    srse_shift_mm<<<(nrows + ROWS2 - 1) / ROWS2, 256, 0, stream>>>(
        sent, w, bsh, shift_idx, cnt, wl, out);
}

// Round 2
// 241.905 us; speedup vs baseline: 1.9619x; 1.9619x over previous
//
#include <hip/hip_runtime.h>

#define B_    16
#define L_    2048
#define S_    1024
#define DE_   512
#define D_    256
#define NSIL_ 8
#define A_    64
#define MS_   (B_ * S_)   // 16384 sentence rows

// GEMM tile
#define BM 64
#define BN 64
#define BK 32

// ---------------------------------------------------------------------------
// Dense GEMM: P[m][n] = sum_k sent[m][k] * w[k][n] + b[n]   (fp32 vector ALU;
// no fp32 MFMA on CDNA4). M=16384, K=512, N=256.
// A staged transposed in LDS with kk-dependent XOR swizzle so both the
// scalar staging writes and the ds_read_b128 fragment reads are <=2-way
// bank aliased (free on CDNA4).
// ---------------------------------------------------------------------------
__global__ __launch_bounds__(256) void srse_gemm(
    const float* __restrict__ sent,   // (MS_, DE_)
    const float* __restrict__ w,      // (DE_, D_)
    const float* __restrict__ bsh,    // (D_)
    float*       __restrict__ P)      // (MS_, D_)
{
    __shared__ float As[BK * BM];     // [kk][m^swz(kk)]
    __shared__ float Bs[BK * BN];     // [kk][n]

    const int t   = threadIdx.x;
    const int bm  = blockIdx.x >> 2;          // 256 row-blocks
    const int bn  = blockIdx.x & 3;           // 4 col-blocks
    const int gm0 = bm * BM;
    const int gn0 = bn * BN;

    const int tm = (t & 15) * 4;              // 16 x 16 thread grid, 4x4 each
    const int tn = (t >> 4) * 4;

    float acc[4][4] = {};

    for (int k0 = 0; k0 < DE_; k0 += BK) {
        // ---- stage A: 64 rows x 32 k, transposed + swizzled ----
        // ---- stage B: 32 k x 64 n, natural ----
        #pragma unroll
        for (int h = 0; h < 2; ++h) {
            const int idx = t + h * 256;

            const int arow = idx >> 3;        // 0..63  (M index)
            const int ac   = idx & 7;         // 0..7   (k float4 slot)
            const float4 av = *(const float4*)(sent + (size_t)(gm0 + arow) * DE_ + k0 + ac * 4);
            const int swz = (ac & 3) << 2;    // == ((kk>>2)&3)<<2 for kk=ac*4+j
            const int pm  = arow ^ swz;
            As[(ac * 4 + 0) * BM + pm] = av.x;
            As[(ac * 4 + 1) * BM + pm] = av.y;
            As[(ac * 4 + 2) * BM + pm] = av.z;
            As[(ac * 4 + 3) * BM + pm] = av.w;

            const int bkk = idx >> 4;         // 0..31
            const int bc  = idx & 15;         // 0..15
            *(float4*)(Bs + bkk * BN + bc * 4) =
                *(const float4*)(w + (size_t)(k0 + bkk) * D_ + gn0 + bc * 4);
        }
        __syncthreads();

        #pragma unroll
        for (int kk = 0; kk < BK; ++kk) {
            const int swz = ((kk >> 2) & 3) << 2;
            const float4 a4 = *(const float4*)(As + kk * BM + (tm ^ swz));
            const float4 b4 = *(const float4*)(Bs + kk * BN + tn);
            const float a[4] = {a4.x, a4.y, a4.z, a4.w};
            const float b[4] = {b4.x, b4.y, b4.z, b4.w};
            #pragma unroll
            for (int i = 0; i < 4; ++i)
                #pragma unroll
                for (int j = 0; j < 4; ++j)
                    acc[i][j] += a[i] * b[j];
        }
        __syncthreads();
    }

    const float4 bv = *(const float4*)(bsh + gn0 + tn);
    #pragma unroll
    for (int i = 0; i < 4; ++i) {
        float4 o;
        o.x = acc[i][0] + bv.x;
        o.y = acc[i][1] + bv.y;
        o.z = acc[i][2] + bv.z;
        o.w = acc[i][3] + bv.w;
        *(float4*)(P + (size_t)(gm0 + tm + i) * D_ + gn0 + tn) = o;
    }
}

// ---------------------------------------------------------------------------
// Select/gather: one wave per output row; wave-uniform branch on item_type;
// 64 lanes x float4 = one 1 KB row copy per wave.
// ---------------------------------------------------------------------------
__global__ __launch_bounds__(256) void srse_select(
    const float* __restrict__ P,          // (MS_, D_)
    const float* __restrict__ op_emb,     // (VOP, D_)
    const float* __restrict__ silent,     // (NSIL_, D_)
    const float* __restrict__ nodes,      // (NN, D_)
    const int*   __restrict__ op_tokens,  // (B*L)
    const int*   __restrict__ arg_idx,    // (B*L)
    const int*   __restrict__ shift_idx,  // (B*L)
    const int*   __restrict__ item_type,  // (B*L)
    const int*   __restrict__ avail,      // (B*L, A_)
    float*       __restrict__ out)        // (B*L, D_)
{
    const int row  = blockIdx.x * 4 + (threadIdx.x >> 6);
    const int lane = threadIdx.x & 63;

    const int t = item_type[row];         // wave-uniform -> s_load
    float4 v = {0.0f, 0.0f, 0.0f, 0.0f};

    if (t == 0) {
        v = *(const float4*)(op_emb + (size_t)op_tokens[row] * D_ + lane * 4);
    } else if (t == 1) {
        const int a = arg_idx[row];
        if (a < NSIL_) {
            v = *(const float4*)(silent + (size_t)a * D_ + lane * 4);
        } else {
            int np = a - NSIL_;
            if (np > A_ - 1) np = A_ - 1;
            const int nid = avail[(size_t)row * A_ + np];
            v = *(const float4*)(nodes + (size_t)nid * D_ + lane * 4);
        }
    } else if (t == 2) {
        const int b = row >> 11;          // row / L_
        const int s = shift_idx[row];
        v = *(const float4*)(P + (size_t)(b * S_ + s) * D_ + lane * 4);
    }

    *(float4*)(out + (size_t)row * D_ + lane * 4) = v;
}

// ---------------------------------------------------------------------------
extern "C" void kernel_launch(void* const* d_in, const int* in_sizes, int n_in,
                              void* d_out, int out_size, void* d_ws, size_t ws_size,
                              hipStream_t stream) {
    const float* sent      = (const float*)d_in[0];
    const float* nodes     = (const float*)d_in[1];
    const float* silent    = (const float*)d_in[2];
    const float* op_emb    = (const float*)d_in[3];
    const float* w         = (const float*)d_in[4];
    const float* bsh       = (const float*)d_in[5];
    const int*   op_tokens = (const int*)d_in[6];
    const int*   arg_idx   = (const int*)d_in[7];
    const int*   shift_idx = (const int*)d_in[8];
    const int*   item_type = (const int*)d_in[9];
    const int*   avail     = (const int*)d_in[10];
    float*       out       = (float*)d_out;

    float* P = (float*)d_ws;              // 16384 x 256 f32 = 16 MiB scratch

    srse_gemm<<<(MS_ / BM) * (D_ / BN), 256, 0, stream>>>(sent, w, bsh, P);

    srse_select<<<(B_ * L_) / 4, 256, 0, stream>>>(
        P, op_emb, silent, nodes, op_tokens, arg_idx, shift_idx, item_type,
        avail, out);
}

// Round 4
// 205.715 us; speedup vs baseline: 2.3070x; 1.1759x over previous
//
#include <hip/hip_runtime.h>

#define B_    16
#define L_    2048
#define S_    1024
#define DE_   512
#define D_    256
#define NSIL_ 8
#define A_    64
#define MS_   (B_ * S_)   // 16384 sentence rows

// GEMM tile: 128x64, BK=64, 4 waves (2x2), per-wave 64x32 via 16x16x32 MFMA
#define BM 128
#define BN 64
#define BK 64

typedef __attribute__((ext_vector_type(8))) short  short8;
typedef __attribute__((ext_vector_type(4))) float  f32x4;

// fp32 -> bf16 round-to-nearest-even (manual; no header type games)
__device__ __forceinline__ unsigned short f2bf(float f) {
    unsigned int x = __builtin_bit_cast(unsigned int, f);
    x += 0x7fffu + ((x >> 16) & 1u);
    return (unsigned short)(x >> 16);
}

// ---------------------------------------------------------------------------
// Tiny: wT[n][k] = bf16(w[k][n])   (256 x 512 bf16 = 256 KB, one-time)
// ---------------------------------------------------------------------------
__global__ __launch_bounds__(256) void srse_wt(
    const float* __restrict__ w, unsigned short* __restrict__ wT)
{
    const int k = blockIdx.x;        // 0..511
    const int n = threadIdx.x;       // 0..255
    wT[n * DE_ + k] = f2bf(w[k * D_ + n]);
}

// ---------------------------------------------------------------------------
// bf16 MFMA GEMM: P = sent @ w + b.  M=16384 K=512 N=256.
// A (f32) converted to bf16 in-register during staging; B from wT (bf16).
// LDS tiles XOR-swizzled so ds_read_b128 fragment reads are conflict-free
// (T2 pattern, m214 G4).
// ---------------------------------------------------------------------------
__global__ __launch_bounds__(256) void srse_gemm(
    const float*          __restrict__ sent,  // (MS_, DE_) f32
    const unsigned short* __restrict__ wT,    // (D_, DE_)  bf16
    const float*          __restrict__ bsh,   // (D_)
    float*                __restrict__ P)     // (MS_, D_)
{
    __shared__ alignas(16) unsigned short As[BM * BK]; // [row][k] swizzled
    __shared__ alignas(16) unsigned short Bs[BN * BK]; // [n][k]   swizzled

    // XCD-chunked swizzle: nwg=512, 512%8==0 -> bijective simple form.
    const int nwg  = (MS_ / BM) * (D_ / BN);           // 512
    const int wg   = (blockIdx.x & 7) * (nwg / 8) + (blockIdx.x >> 3);
    const int bm   = wg >> 2;                          // 0..127
    const int bn   = wg & 3;                           // 0..3
    const int gm0  = bm * BM;
    const int gn0  = bn * BN;

    const int t    = threadIdx.x;
    const int lane = t & 63;
    const int wid  = t >> 6;
    const int wm   = wid & 1;                          // m-half (64 rows)
    const int wn   = wid >> 1;                         // n-half (32 cols)
    const int fr   = lane & 15;                        // fragment row/col
    const int fq   = lane >> 4;                        // fragment quadrant

    f32x4 acc[4][2] = {};

    for (int k0 = 0; k0 < DE_; k0 += BK) {
        // ---- stage A: 128 rows x 64 k (f32 -> bf16) ----
        #pragma unroll
        for (int s = 0; s < 4; ++s) {
            const int id  = s * 256 + t;
            const int row = id >> 3;                   // 0..127
            const int k8  = id & 7;                    // 8-bf16 slot
            const float4 a0 = *(const float4*)(sent + (size_t)(gm0 + row) * DE_ + k0 + k8 * 8);
            const float4 a1 = *(const float4*)(sent + (size_t)(gm0 + row) * DE_ + k0 + k8 * 8 + 4);
            short8 v;
            v[0] = f2bf(a0.x); v[1] = f2bf(a0.y); v[2] = f2bf(a0.z); v[3] = f2bf(a0.w);
            v[4] = f2bf(a1.x); v[5] = f2bf(a1.y); v[6] = f2bf(a1.z); v[7] = f2bf(a1.w);
            const int widx = (row * BK + k8 * 8) ^ ((row & 7) << 3); // ushort units
            *(short8*)(As + widx) = v;
        }
        // ---- stage B: 64 n x 64 k (bf16 passthrough) ----
        #pragma unroll
        for (int s = 0; s < 2; ++s) {
            const int id = s * 256 + t;
            const int n  = id >> 3;                    // 0..63
            const int k8 = id & 7;
            short8 v = *(const short8*)(wT + (size_t)(gn0 + n) * DE_ + k0 + k8 * 8);
            const int widx = (n * BK + k8 * 8) ^ ((n & 7) << 3);
            *(short8*)(Bs + widx) = v;
        }
        __syncthreads();

        #pragma unroll
        for (int ks = 0; ks < 2; ++ks) {               // two K=32 sub-steps
            short8 af[4], bf[2];
            #pragma unroll
            for (int mf = 0; mf < 4; ++mf) {
                const int row = wm * 64 + mf * 16 + fr;
                af[mf] = *(const short8*)(As + ((row * BK + ks * 32 + fq * 8) ^ ((row & 7) << 3)));
            }
            #pragma unroll
            for (int nf = 0; nf < 2; ++nf) {
                const int n = wn * 32 + nf * 16 + fr;
                bf[nf] = *(const short8*)(Bs + ((n * BK + ks * 32 + fq * 8) ^ ((n & 7) << 3)));
            }
            #pragma unroll
            for (int mf = 0; mf < 4; ++mf)
                #pragma unroll
                for (int nf = 0; nf < 2; ++nf)
                    acc[mf][nf] = __builtin_amdgcn_mfma_f32_16x16x32_bf16(
                        af[mf], bf[nf], acc[mf][nf], 0, 0, 0);
        }
        __syncthreads();
    }

    // epilogue: C/D layout col=lane&15, row=(lane>>4)*4+r  [m89-verified]
    #pragma unroll
    for (int nf = 0; nf < 2; ++nf) {
        const int col = gn0 + wn * 32 + nf * 16 + fr;
        const float bval = bsh[col];
        #pragma unroll
        for (int mf = 0; mf < 4; ++mf) {
            #pragma unroll
            for (int r = 0; r < 4; ++r) {
                const int row = gm0 + wm * 64 + mf * 16 + fq * 4 + r;
                P[(size_t)row * D_ + col] = acc[mf][nf][r] + bval;
            }
        }
    }
}

// ---------------------------------------------------------------------------
// Select/gather: 8 rows per wave, branchless pointer select -> 8 independent
// gather chains in flight per wave.
// ---------------------------------------------------------------------------
__global__ __launch_bounds__(256) void srse_select(
    const float* __restrict__ P,          // (MS_, D_)
    const float* __restrict__ op_emb,     // (VOP, D_)
    const float* __restrict__ silent,     // (NSIL_, D_)
    const float* __restrict__ nodes,      // (NN, D_)
    const int*   __restrict__ op_tokens,  // (B*L)
    const int*   __restrict__ arg_idx,    // (B*L)
    const int*   __restrict__ shift_idx,  // (B*L)
    const int*   __restrict__ item_type,  // (B*L)
    const int*   __restrict__ avail,      // (B*L, A_)
    float*       __restrict__ out)        // (B*L, D_)
{
    const int wid  = threadIdx.x >> 6;
    const int lane = threadIdx.x & 63;
    const int r0   = blockIdx.x * 32 + wid * 8;

    const float* src[8];
    #pragma unroll
    for (int i = 0; i < 8; ++i) {
        const int row = r0 + i;
        const int tt  = item_type[row];
        const int a   = arg_idx[row];
        int np = a - NSIL_;
        np = np < 0 ? 0 : (np > A_ - 1 ? A_ - 1 : np);
        const float* s0 = op_emb + (size_t)op_tokens[row] * D_;
        const float* s1 = (a < NSIL_)
                          ? silent + (size_t)a * D_
                          : nodes + (size_t)avail[(size_t)row * A_ + np] * D_;
        const float* s2 = P + (size_t)((row >> 11) * S_ + shift_idx[row]) * D_;
        src[i] = (tt == 0) ? s0 : ((tt == 1) ? s1 : s2);
    }

    float4 v[8];
    #pragma unroll
    for (int i = 0; i < 8; ++i)
        v[i] = *(const float4*)(src[i] + lane * 4);

    #pragma unroll
    for (int i = 0; i < 8; ++i)
        *(float4*)(out + (size_t)(r0 + i) * D_ + lane * 4) = v[i];
}

// ---------------------------------------------------------------------------
extern "C" void kernel_launch(void* const* d_in, const int* in_sizes, int n_in,
                              void* d_out, int out_size, void* d_ws, size_t ws_size,
                              hipStream_t stream) {
    const float* sent      = (const float*)d_in[0];
    const float* nodes     = (const float*)d_in[1];
    const float* silent    = (const float*)d_in[2];
    const float* op_emb    = (const float*)d_in[3];
    const float* w         = (const float*)d_in[4];
    const float* bsh       = (const float*)d_in[5];
    const int*   op_tokens = (const int*)d_in[6];
    const int*   arg_idx   = (const int*)d_in[7];
    const int*   shift_idx = (const int*)d_in[8];
    const int*   item_type = (const int*)d_in[9];
    const int*   avail     = (const int*)d_in[10];
    float*       out       = (float*)d_out;

    unsigned short* wT = (unsigned short*)d_ws;              // 256 KB bf16
    float*          P  = (float*)((char*)d_ws + D_ * DE_ * sizeof(unsigned short));

    srse_wt<<<DE_, 256, 0, stream>>>(w, wT);

    srse_gemm<<<(MS_ / BM) * (D_ / BN), 256, 0, stream>>>(sent, wT, bsh, P);

    srse_select<<<(B_ * L_) / 32, 256, 0, stream>>>(
        P, op_emb, silent, nodes, op_tokens, arg_idx, shift_idx, item_type,
        avail, out);
}